// Round 1
// baseline (838.349 us; speedup 1.0000x reference)
//
#include <hip/hip_runtime.h>
#include <cmath>

// ---------------- constants ----------------
// B=4096, M=8, HSS=128, HID=1024, NIN=8, DIN=128, IH=4, KDIM=64, VDIM=128,
// T=4, TOPK=4, CH=4, CDK=32, CDV=32
#define NB 4096
#define HIDX 1024

// d_out layout (floats): hx_out[4194304] | mask_full[4194304] | block_mask[32768] | temp_att[131072]

__device__ __forceinline__ float sigm(float x) { return 1.0f / (1.0f + expf(-x)); }

// ---------------- K0: weight prep ----------------
// Wvm[i][d]  = mean over 4 heads of Wv_in[i][h*128+d]        (128x128)
// WihT[i][c] = W_ih[c][i]  c = t*384 + gate*128 + j          (128x1536)
// WhhT[i][c] = W_hh[c][i]                                     (128x1536)
__global__ __launch_bounds__(256) void k0_prep(
    const float* __restrict__ Wv_in, const float* __restrict__ W_ih,
    const float* __restrict__ W_hh, float* __restrict__ Wvm,
    float* __restrict__ WihT, float* __restrict__ WhhT)
{
    int idx = blockIdx.x * 256 + threadIdx.x;
    if (idx < 16384) {
        int i = idx >> 7, d = idx & 127;
        const float* p = Wv_in + i * 512 + d;
        Wvm[idx] = 0.25f * (p[0] + p[128] + p[256] + p[384]);
    } else if (idx < 16384 + 196608) {
        int o = idx - 16384;
        int i = o / 1536, c = o - i * 1536;
        WihT[o] = W_ih[c * 128 + i];
    } else if (idx < 16384 + 2 * 196608) {
        int o = idx - 16384 - 196608;
        int i = o / 1536, c = o - i * 1536;
        WhhT[o] = W_hh[c * 128 + i];
    }
}

// ---------------- K1: input attention ----------------
// one batch element per workgroup, 256 threads
__global__ __launch_bounds__(256) void k1_input_attn(
    const float* __restrict__ inp, const float* __restrict__ hx,
    const float* __restrict__ Wq, const float* __restrict__ Wk,
    const float* __restrict__ Wvm,
    float* iu /*inp_use out (aliases mask_full slot)*/,
    float* __restrict__ maskp, float* __restrict__ block_mask)
{
    int b = blockIdx.x;
    int tid = threadIdx.x;
    __shared__ float hT[128][8];   // [feat][m]
    __shared__ float xT[128][8];   // [feat][n]
    __shared__ float QT[256][8];   // [c][m]
    __shared__ float KT[256][8];   // [c][n]
    __shared__ float V[8][128];    // [n][d]
    __shared__ float S[8][8];
    __shared__ float P[8][9];
    __shared__ float nnull[8];
    __shared__ float maskS[8];

    { // stage h,x transposed
        float4 hv = reinterpret_cast<const float4*>(hx + b * HIDX)[tid];
        float4 xv = reinterpret_cast<const float4*>(inp + b * HIDX)[tid];
        int g = tid * 4;
        int m = g >> 7, i0 = g & 127;
        hT[i0 + 0][m] = hv.x; hT[i0 + 1][m] = hv.y; hT[i0 + 2][m] = hv.z; hT[i0 + 3][m] = hv.w;
        xT[i0 + 0][m] = xv.x; xT[i0 + 1][m] = xv.y; xT[i0 + 2][m] = xv.z; xT[i0 + 3][m] = xv.w;
    }
    __syncthreads();
    { // Q = h@Wq, K = x@Wk : thread owns column j = tid (256 cols)
        int j = tid;
        float aq[8] = {0, 0, 0, 0, 0, 0, 0, 0};
        float ak[8] = {0, 0, 0, 0, 0, 0, 0, 0};
        for (int i = 0; i < 128; ++i) {
            float wq = Wq[i * 256 + j];
            float wk = Wk[i * 256 + j];
#pragma unroll
            for (int m = 0; m < 8; ++m) {
                aq[m] = fmaf(hT[i][m], wq, aq[m]);
                ak[m] = fmaf(xT[i][m], wk, ak[m]);
            }
        }
#pragma unroll
        for (int m = 0; m < 8; ++m) { QT[j][m] = aq[m]; KT[j][m] = ak[m]; }
    }
    { // V = x@Wvm : thread owns (d = tid&127, 4 n's)
        int d = tid & 127;
        int n0 = (tid >> 7) * 4;
        float av[4] = {0, 0, 0, 0};
        for (int i = 0; i < 128; ++i) {
            float w = Wvm[i * 128 + d];
#pragma unroll
            for (int p = 0; p < 4; ++p) av[p] = fmaf(xT[i][n0 + p], w, av[p]);
        }
#pragma unroll
        for (int p = 0; p < 4; ++p) V[n0 + p][d] = av[p];
    }
    __syncthreads();
    if (tid < 64) { // scores: full 256-dot / 32 (collapses head mean)
        int m = tid >> 3, n = tid & 7;
        float s = 0.0f;
        for (int c = 0; c < 256; ++c) s = fmaf(QT[c][m], KT[c][n], s);
        S[m][n] = s * (1.0f / 32.0f);
    }
    __syncthreads();
    if (tid < 8) { // softmax over 9 (null col score == 0), notnull
        int m = tid;
        float mx = 0.0f; // null score = 0 participates in max
        for (int n = 0; n < 8; ++n) mx = fmaxf(mx, S[m][n]);
        float en = expf(0.0f - mx);
        float sum = en;
        float e[8];
        for (int n = 0; n < 8; ++n) { e[n] = expf(S[m][n] - mx); sum += e[n]; }
        float inv = 1.0f / sum;
        for (int n = 0; n < 8; ++n) P[m][n] = e[n] * inv;
        nnull[m] = 1.0f - en * inv;
    }
    __syncthreads();
    if (tid == 0) { // strict top-4 (ties -> lower index, matches lax.top_k)
        unsigned sel = 0;
        for (int s = 0; s < 4; ++s) {
            int best = 0; float bv = -3.0e38f;
            for (int m = 0; m < 8; ++m)
                if (!(sel & (1u << m)) && nnull[m] > bv) { bv = nnull[m]; best = m; }
            sel |= 1u << best;
        }
        for (int m = 0; m < 8; ++m) maskS[m] = (sel & (1u << m)) ? 1.0f : 0.0f;
    }
    __syncthreads();
    { // out = P@V * mask -> inp_use
        int m = tid >> 5;
        int d0 = (tid & 31) * 4;
        float acc[4] = {0, 0, 0, 0};
#pragma unroll
        for (int n = 0; n < 8; ++n) {
            float p = P[m][n];
#pragma unroll
            for (int q = 0; q < 4; ++q) acc[q] = fmaf(p, V[n][d0 + q], acc[q]);
        }
        float mk = maskS[m];
        reinterpret_cast<float4*>(iu + b * HIDX + m * 128 + d0)[0] =
            make_float4(acc[0] * mk, acc[1] * mk, acc[2] * mk, acc[3] * mk);
    }
    if (tid < 8) {
        maskp[b * 8 + tid] = maskS[tid];
        block_mask[b * 8 + tid] = maskS[tid];
    }
}

// ---------------- K2: shared block GRU ----------------
// 2 batch elements (16 rows) per workgroup, 256 threads
__global__ __launch_bounds__(256) void k2_gru(
    float* iu /*in: inp_use, out: mask_full (same memory)*/,
    const float* __restrict__ hx,
    const float* __restrict__ WihT, const float* __restrict__ WhhT,
    const float* __restrict__ b_ih, const float* __restrict__ b_hh,
    const float* __restrict__ W_read, const float* __restrict__ W_write,
    const float* __restrict__ maskp,
    float* __restrict__ hnew_out /*d_out hx slot*/, float* __restrict__ temp_att)
{
    int b0 = blockIdx.x * 2;
    int tid = threadIdx.x;
    __shared__ float xT[128][16];      // [feat][row]
    __shared__ float hT[128][16];
    __shared__ float hnext[16][516];   // pad 516: kills bank conflict in w_key phase
    __shared__ float hread[16][16];
    __shared__ float wkey[16][4][16];
    __shared__ float attS[16][4];

    { // stage transposed; then overwrite inp_use region with final mask_full
#pragma unroll
        for (int q = 0; q < 2; ++q) {
            int idx = tid + q * 256;
            float4 xv = reinterpret_cast<const float4*>(iu + b0 * HIDX)[idx];
            float4 hv = reinterpret_cast<const float4*>(hx + b0 * HIDX)[idx];
            int g = idx * 4;
            int r = g >> 7, i0 = g & 127;
            xT[i0 + 0][r] = xv.x; xT[i0 + 1][r] = xv.y; xT[i0 + 2][r] = xv.z; xT[i0 + 3][r] = xv.w;
            hT[i0 + 0][r] = hv.x; hT[i0 + 1][r] = hv.y; hT[i0 + 2][r] = hv.z; hT[i0 + 3][r] = hv.w;
            float mkv = maskp[b0 * 8 + r];
            reinterpret_cast<float4*>(iu + b0 * HIDX)[idx] = make_float4(mkv, mkv, mkv, mkv);
        }
    }
    __syncthreads();
    int j = tid & 127;
    int r0 = (tid >> 7) * 8;
    for (int t = 0; t < 4; ++t) {
        float gir[8] = {0,0,0,0,0,0,0,0}, giz[8] = {0,0,0,0,0,0,0,0}, gin[8] = {0,0,0,0,0,0,0,0};
        float ghr[8] = {0,0,0,0,0,0,0,0}, ghz[8] = {0,0,0,0,0,0,0,0}, ghn[8] = {0,0,0,0,0,0,0,0};
        const float* wih = WihT + t * 384 + j;
        const float* whh = WhhT + t * 384 + j;
        for (int i = 0; i < 128; ++i) {
            float wir = wih[i * 1536];
            float wiz = wih[i * 1536 + 128];
            float win = wih[i * 1536 + 256];
            float whr = whh[i * 1536];
            float whz = whh[i * 1536 + 128];
            float whn = whh[i * 1536 + 256];
#pragma unroll
            for (int p = 0; p < 8; ++p) {
                float xv = xT[i][r0 + p], hv = hT[i][r0 + p];
                gir[p] = fmaf(xv, wir, gir[p]);
                giz[p] = fmaf(xv, wiz, giz[p]);
                gin[p] = fmaf(xv, win, gin[p]);
                ghr[p] = fmaf(hv, whr, ghr[p]);
                ghz[p] = fmaf(hv, whz, ghz[p]);
                ghn[p] = fmaf(hv, whn, ghn[p]);
            }
        }
        float bir = b_ih[t * 384 + j], biz = b_ih[t * 384 + 128 + j], bin = b_ih[t * 384 + 256 + j];
        float bhr = b_hh[t * 384 + j], bhz = b_hh[t * 384 + 128 + j], bhn = b_hh[t * 384 + 256 + j];
#pragma unroll
        for (int p = 0; p < 8; ++p) {
            int r = r0 + p;
            float rr = sigm(gir[p] + bir + ghr[p] + bhr);
            float zz = sigm(giz[p] + biz + ghz[p] + bhz);
            float nn = tanhf(gin[p] + bin + rr * (ghn[p] + bhn));
            hnext[r][t * 128 + j] = (1.0f - zz) * nn + zz * hT[j][r];
        }
    }
    __syncthreads();
    { // h_read (16x16) and w_key (16x4x16)
        int r = tid >> 4, k = tid & 15;
        float acc = 0.0f;
        for (int h = 0; h < 128; ++h) acc = fmaf(hT[h][r], W_read[h * 16 + k], acc);
        hread[r][k] = acc;
        for (int t = 0; t < 4; ++t) {
            float a2 = 0.0f;
            for (int h = 0; h < 128; ++h)
                a2 = fmaf(hnext[r][t * 128 + h], W_write[(t * 128 + h) * 16 + k], a2);
            wkey[r][t][k] = a2;
        }
    }
    __syncthreads();
    if (tid < 16) { // template softmax
        int r = tid;
        float lg[4];
        for (int t = 0; t < 4; ++t) {
            float s = 0.0f;
            for (int k = 0; k < 16; ++k) s = fmaf(hread[r][k], wkey[r][t][k], s);
            lg[t] = s * 0.25f;
        }
        float mx = fmaxf(fmaxf(lg[0], lg[1]), fmaxf(lg[2], lg[3]));
        float e[4], sum = 0.0f;
        for (int t = 0; t < 4; ++t) { e[t] = expf(lg[t] - mx); sum += e[t]; }
        float inv = 1.0f / sum;
        for (int t = 0; t < 4; ++t) {
            float a = e[t] * inv;
            attS[r][t] = a;
            temp_att[(b0 * 8 + r) * 4 + t] = a;
        }
    }
    __syncthreads();
    { // hnew = sum_t att[t] * hnext[t]
        int r = tid >> 4;
        int h0 = (tid & 15) * 8;
        float o[8] = {0, 0, 0, 0, 0, 0, 0, 0};
#pragma unroll
        for (int t = 0; t < 4; ++t) {
            float a = attS[r][t];
#pragma unroll
            for (int q = 0; q < 8; ++q) o[q] = fmaf(a, hnext[r][t * 128 + h0 + q], o[q]);
        }
        float* dst = hnew_out + (b0 + (r >> 3)) * HIDX + (r & 7) * 128 + h0;
        reinterpret_cast<float4*>(dst)[0] = make_float4(o[0], o[1], o[2], o[3]);
        reinterpret_cast<float4*>(dst)[1] = make_float4(o[4], o[5], o[6], o[7]);
    }
}

// ---------------- K3: comm attention + final select ----------------
// 2 batch elements per workgroup; reads hnew from hio, writes hx_out in place
__global__ __launch_bounds__(256) void k3_comm(
    const float* __restrict__ hx, const float* __restrict__ maskp,
    const float* __restrict__ Wq_c, const float* __restrict__ bq_c,
    const float* __restrict__ Wk_c, const float* __restrict__ bk_c,
    const float* __restrict__ Wv_c, const float* __restrict__ bv_c,
    const float* __restrict__ W_fc, const float* __restrict__ b_fc,
    const float* __restrict__ W_g, const float* __restrict__ b_g,
    float* hio)
{
    int b0 = blockIdx.x * 2;
    int tid = threadIdx.x;
    __shared__ float hT[128][16];   // hnew transposed [feat][row]
    __shared__ float qT[128][16];   // [c][row]
    __shared__ float kT[128][16];
    __shared__ float vN[16][128];   // natural [row][c]
    __shared__ float P[2][4][8][8]; // [b'][ch][m][n]
    __shared__ float outT[128][16]; // [c][row]
    __shared__ float fco[16][128];
    __shared__ float gco[16][128];

    {
#pragma unroll
        for (int q = 0; q < 2; ++q) {
            int idx = tid + q * 256;
            float4 hv = reinterpret_cast<const float4*>(hio + b0 * HIDX)[idx];
            int g = idx * 4;
            int r = g >> 7, i0 = g & 127;
            hT[i0 + 0][r] = hv.x; hT[i0 + 1][r] = hv.y; hT[i0 + 2][r] = hv.z; hT[i0 + 3][r] = hv.w;
        }
    }
    __syncthreads();
    { // q,k,v = h@W + b : thread owns (b' = tid>>7, col jj = tid&127)
        int jj = tid & 127;
        int r0 = (tid >> 7) * 8;
        float aq[8] = {0,0,0,0,0,0,0,0}, ak[8] = {0,0,0,0,0,0,0,0}, av[8] = {0,0,0,0,0,0,0,0};
        for (int i = 0; i < 128; ++i) {
            float wq = Wq_c[i * 128 + jj];
            float wk = Wk_c[i * 128 + jj];
            float wv = Wv_c[i * 128 + jj];
#pragma unroll
            for (int p = 0; p < 8; ++p) {
                float h = hT[i][r0 + p];
                aq[p] = fmaf(h, wq, aq[p]);
                ak[p] = fmaf(h, wk, ak[p]);
                av[p] = fmaf(h, wv, av[p]);
            }
        }
        float bq = bq_c[jj], bk = bk_c[jj], bv = bv_c[jj];
#pragma unroll
        for (int p = 0; p < 8; ++p) {
            qT[jj][r0 + p] = aq[p] + bq;
            kT[jj][r0 + p] = ak[p] + bk;
            vN[r0 + p][jj] = av[p] + bv;
        }
    }
    __syncthreads();
    if (tid < 64) { // per-head scores + softmax: (b',ch,m)
        int bp = tid >> 5, ch = (tid >> 3) & 3, m = tid & 7;
        int r = bp * 8 + m;
        float s[8] = {0, 0, 0, 0, 0, 0, 0, 0};
        for (int d = 0; d < 32; ++d) {
            float qv = qT[ch * 32 + d][r];
#pragma unroll
            for (int n = 0; n < 8; ++n) s[n] = fmaf(qv, kT[ch * 32 + d][bp * 8 + n], s[n]);
        }
        const float scl = 0.17677669529663687f; // 1/sqrt(32)
        float mx = -3.0e38f;
        for (int n = 0; n < 8; ++n) { s[n] *= scl; mx = fmaxf(mx, s[n]); }
        float e[8], sum = 0.0f;
        for (int n = 0; n < 8; ++n) { e[n] = expf(s[n] - mx); sum += e[n]; }
        float inv = 1.0f / sum;
        for (int n = 0; n < 8; ++n) P[bp][ch][m][n] = e[n] * inv;
    }
    __syncthreads();
    { // out = attn @ v  -> outT
        int r = tid >> 4, bp = r >> 3, m = r & 7;
        int c0 = (tid & 15) * 8, ch = c0 >> 5;
        float acc[8] = {0, 0, 0, 0, 0, 0, 0, 0};
#pragma unroll
        for (int n = 0; n < 8; ++n) {
            float p = P[bp][ch][m][n];
#pragma unroll
            for (int q = 0; q < 8; ++q) acc[q] = fmaf(p, vN[bp * 8 + n][c0 + q], acc[q]);
        }
#pragma unroll
        for (int q = 0; q < 8; ++q) outT[c0 + q][r] = acc[q];
    }
    __syncthreads();
    { // fc and gate GEMMs: (mat = tid>>7, jj = tid&127), 16 rows each
        int mat = tid >> 7, jj = tid & 127;
        const float* W = mat ? W_g : W_fc;
        float acc[16] = {0,0,0,0,0,0,0,0,0,0,0,0,0,0,0,0};
        for (int i = 0; i < 128; ++i) {
            float w = W[i * 128 + jj];
#pragma unroll
            for (int r = 0; r < 16; ++r) acc[r] = fmaf(outT[i][r], w, acc[r]);
        }
        if (mat == 0) {
            float bb = b_fc[jj];
            for (int r = 0; r < 16; ++r) fco[r][jj] = acc[r] + bb;
        } else {
            float bb = b_g[jj];
            for (int r = 0; r < 16; ++r) gco[r][jj] = acc[r] + bb;
        }
    }
    __syncthreads();
    { // final: att_out = sigm(gate)*tanh(fc); hx_out = mask ? hnew+att_out : hx
        int r = tid >> 4, j0 = (tid & 15) * 8;
        int b = b0 + (r >> 3), m = r & 7;
        float mk = maskp[b * 8 + m];
        float res[8];
#pragma unroll
        for (int q = 0; q < 8; ++q) {
            int jj = j0 + q;
            float ao = sigm(gco[r][jj]) * tanhf(fco[r][jj]);
            float hn = hT[jj][r] + ao;
            float ho = hx[b * HIDX + m * 128 + jj];
            res[q] = mk * hn + (1.0f - mk) * ho;
        }
        float* dst = hio + b * HIDX + m * 128 + j0;
        reinterpret_cast<float4*>(dst)[0] = make_float4(res[0], res[1], res[2], res[3]);
        reinterpret_cast<float4*>(dst)[1] = make_float4(res[4], res[5], res[6], res[7]);
    }
}

// ---------------- launch ----------------
extern "C" void kernel_launch(void* const* d_in, const int* in_sizes, int n_in,
                              void* d_out, int out_size, void* d_ws, size_t ws_size,
                              hipStream_t stream)
{
    const float* inp     = (const float*)d_in[0];
    const float* hx      = (const float*)d_in[1];
    const float* Wq_in   = (const float*)d_in[3];
    const float* Wk_in   = (const float*)d_in[4];
    const float* Wv_in   = (const float*)d_in[5];
    const float* W_ih    = (const float*)d_in[6];
    const float* b_ih    = (const float*)d_in[7];
    const float* W_hh    = (const float*)d_in[8];
    const float* b_hh    = (const float*)d_in[9];
    const float* W_read  = (const float*)d_in[10];
    const float* W_write = (const float*)d_in[11];
    const float* Wq_c    = (const float*)d_in[12];
    const float* bq_c    = (const float*)d_in[13];
    const float* Wk_c    = (const float*)d_in[14];
    const float* bk_c    = (const float*)d_in[15];
    const float* Wv_c    = (const float*)d_in[16];
    const float* bv_c    = (const float*)d_in[17];
    const float* W_fc    = (const float*)d_in[18];
    const float* b_fc    = (const float*)d_in[19];
    const float* W_g     = (const float*)d_in[20];
    const float* b_g     = (const float*)d_in[21];

    float* out        = (float*)d_out;
    float* hx_out     = out;                 // B*1024
    float* mask_full  = out + 4194304;       // B*1024 (also temp home of inp_use)
    float* block_mask = out + 8388608;       // B*8
    float* temp_att   = out + 8421376;       // B*8*4

    float* ws    = (float*)d_ws;
    float* Wvm   = ws;                       // 16384
    float* WihT  = Wvm + 16384;              // 196608
    float* WhhT  = WihT + 196608;            // 196608
    float* maskp = WhhT + 196608;            // 32768
    // total ws: ~1.73 MB

    k0_prep<<<1600, 256, 0, stream>>>(Wv_in, W_ih, W_hh, Wvm, WihT, WhhT);
    k1_input_attn<<<NB, 256, 0, stream>>>(inp, hx, Wq_in, Wk_in, Wvm,
                                          mask_full /*inp_use*/, maskp, block_mask);
    k2_gru<<<NB / 2, 256, 0, stream>>>(mask_full /*inp_use -> mask_full*/, hx,
                                       WihT, WhhT, b_ih, b_hh, W_read, W_write,
                                       maskp, hx_out /*hnew*/, temp_att);
    k3_comm<<<NB / 2, 256, 0, stream>>>(hx, maskp, Wq_c, bq_c, Wk_c, bk_c,
                                        Wv_c, bv_c, W_fc, b_fc, W_g, b_g, hx_out);
}